// Round 6
// baseline (274.452 us; speedup 1.0000x reference)
//
#include <hip/hip_runtime.h>
#include <hip/hip_bf16.h>

// Problem dims
#define B_ 16
#define L_ 2048
#define DF 512
#define H_ 8
#define DH 512
#define U_ 512

typedef unsigned short u16;
typedef __attribute__((ext_vector_type(8))) short bf16x8;
typedef __attribute__((ext_vector_type(4))) float f32x4;

__device__ __forceinline__ u16 f2bf(float x) {
  __hip_bfloat16 h = __float2bfloat16(x);
  u16 u;
  __builtin_memcpy(&u, &h, 2);
  return u;
}

__device__ __forceinline__ void load_lds16(const void* g, void* l) {
  __builtin_amdgcn_global_load_lds(
      (const __attribute__((address_space(1))) void*)g,
      (__attribute__((address_space(3))) void*)l, 16, 0, 0);
}

// tanh(x) = 1 - 2/(1+e^{2x}); exact at +-inf, ~1e-6 abs err.
__device__ __forceinline__ float fast_tanh2(float x) {
  float e = __expf(2.f * x);
  return 1.f - __fdividef(2.f, e + 1.f);
}

// ---------------------------------------------------------------------------
// Merged conversion kernel:
//  blocks [0, 16384): features fp32 -> bf16 [B,L,DF], 4 elems/thread
//  blocks [16384, 18432): W1 [H,DF,U] -> W1T [H,U,DF] bf16 (32x32 transpose)
// ---------------------------------------------------------------------------
__global__ __launch_bounds__(256) void convert_kernel(
    const float* __restrict__ F, u16* __restrict__ Abf,
    const float* __restrict__ W1, u16* __restrict__ W1T) {
  __shared__ float t[32][33];
  if (blockIdx.x < 16384) {
    size_t i = ((size_t)blockIdx.x * 256 + threadIdx.x) * 4;
    float4 v = *(const float4*)(F + i);
    ushort4 o;
    o.x = f2bf(v.x); o.y = f2bf(v.y); o.z = f2bf(v.z); o.w = f2bf(v.w);
    *(ushort4*)(Abf + i) = o;
  } else {
    int bid = blockIdx.x - 16384;
    int d0 = (bid & 15) * 32, u0 = ((bid >> 4) & 15) * 32, h = bid >> 8;
    const float* src = W1 + (size_t)h * DF * U_;
    u16* dst = W1T + (size_t)h * U_ * DF;
#pragma unroll
    for (int i = 0; i < 4; ++i) {
      int idx = threadIdx.x + i * 256;
      int r = idx >> 5, c = idx & 31;
      t[r][c] = src[(size_t)(d0 + r) * U_ + u0 + c];
    }
    __syncthreads();
#pragma unroll
    for (int i = 0; i < 4; ++i) {
      int idx = threadIdx.x + i * 256;
      int r = idx >> 5, c = idx & 31;  // r: u index, c: d index
      dst[(size_t)(u0 + r) * DF + d0 + c] = f2bf(t[c][r]);
    }
  }
}

// ---------------------------------------------------------------------------
// hproj split-d: partial[z,b,h,u] = sum_{d in chunk z} hidden*W2
// ---------------------------------------------------------------------------
__global__ __launch_bounds__(128) void hproj_part_kernel(
    const float* __restrict__ hidden, const float* __restrict__ W2,
    float* __restrict__ partial) {
  int h = blockIdx.x;
  int u = blockIdx.y * 128 + threadIdx.x;
  int d0 = blockIdx.z * 64;
  __shared__ float hs[B_][64];
  for (int idx = threadIdx.x; idx < B_ * 64; idx += 128) {
    int b = idx >> 6, d = idx & 63;
    hs[b][d] = hidden[(size_t)(b * H_ + h) * DH + d0 + d];
  }
  __syncthreads();
  float acc[B_];
#pragma unroll
  for (int b = 0; b < B_; b++) acc[b] = 0.f;
  const float* w2p = W2 + ((size_t)h * DH + d0) * U_ + u;
  for (int d = 0; d < 64; d++) {
    float w = w2p[(size_t)d * U_];
#pragma unroll
    for (int b = 0; b < B_; b++) acc[b] += hs[b][d] * w;
  }
#pragma unroll
  for (int b = 0; b < B_; b++)
    partial[(((size_t)blockIdx.z * B_ + b) * H_ + h) * U_ + u] = acc[b];
}

__global__ __launch_bounds__(256) void hproj_combine_kernel(
    const float* __restrict__ partial, const float* __restrict__ b1,
    const float* __restrict__ b2, float* __restrict__ c) {
  int i = blockIdx.x * 256 + threadIdx.x;  // over B*H*U
  int hu = i & (H_ * U_ - 1);
  float s = b1[hu] + b2[hu];
#pragma unroll
  for (int z = 0; z < 8; z++) s += partial[(size_t)z * B_ * H_ * U_ + i];
  c[i] = s;
}

// ---------------------------------------------------------------------------
// score kernel, 8-phase 256x256 template (T2+T3+T4+T5):
//  256(M=l) x 256(N=u half) tile, split-U across blocks (combine in softmax),
//  BK=64, 8 waves 2Mx4N (each 128x64), 128 KB LDS double-buffer with XOR
//  source-swizzle, 4 phases/K-tile x 16 MFMA with operand reuse, full-tile
//  prefetch issued at phase 1, single vmcnt(0)+barrier handoff at phase 4.
// grid (16 = 8 mt x 2 ut, B, H), block 512.
// ---------------------------------------------------------------------------
#define BKT 64

__global__ __launch_bounds__(512, 2) void score_kernel(
    const u16* __restrict__ Abf, const u16* __restrict__ W1T,
    const float* __restrict__ C, const float* __restrict__ V,
    float* __restrict__ pscore) {
  int gx = blockIdx.x;
  int mt = gx >> 1, ut = gx & 1;
  int l0 = mt * 256, u0 = ut * 256;
  int b = blockIdx.y, h = blockIdx.z;
  int tid = threadIdx.x;
  int lane = tid & 63, wid = tid >> 6;
  int wr = wid >> 2, wc = wid & 3;  // 2 x 4 waves
  int rl = lane & 15, q = lane >> 4;

  __shared__ u16 As[2][256 * BKT];  // 32 KB each
  __shared__ u16 Bs[2][256 * BKT];
  __shared__ float redsm[4][256];   // 4 KB

  const u16* Fb = Abf + ((size_t)b * L_ + l0) * DF;
  const u16* Wh = W1T + ((size_t)h * U_ + u0) * DF;

  f32x4 acc[8][4];
#pragma unroll
  for (int m = 0; m < 8; ++m)
#pragma unroll
    for (int n = 0; n < 4; ++n)
#pragma unroll
      for (int j = 0; j < 4; ++j) acc[m][n][j] = 0.f;

  // Staging: 2048 16B-chunks per matrix per K-tile; physical chunk (row,ch)
  // holds logical chunk ch ^ (row&7) (involution; same XOR on read side).
#define STAGE(bufi, kb)                                                    \
  {                                                                        \
    _Pragma("unroll") for (int i_ = 0; i_ < 4; ++i_) {                     \
      int idx_ = i_ * 512 + tid;                                           \
      int row_ = idx_ >> 3;                                                \
      int ke_ = ((idx_ & 7) ^ (row_ & 7)) << 3;                            \
      load_lds16(Fb + ((size_t)row_ << 9) + (kb) + ke_,                    \
                 &As[bufi][idx_ * 8]);                                     \
      load_lds16(Wh + ((size_t)row_ << 9) + (kb) + ke_,                    \
                 &Bs[bufi][idx_ * 8]);                                     \
    }                                                                      \
  }

  bf16x8 a[4][2], bA[2][2], bB[2][2];

#define RD_A(mb)                                                           \
  {                                                                        \
    _Pragma("unroll") for (int mm = 0; mm < 4; ++mm)                       \
    _Pragma("unroll") for (int ss = 0; ss < 2; ++ss) {                     \
      int rA = wr * 128 + ((mb) + mm) * 16 + rl;                           \
      a[mm][ss] = *(const bf16x8*)&As[c][(rA << 6) +                       \
                                         (((ss * 4 + q) ^ (rA & 7)) << 3)];\
    }                                                                      \
  }

#define RD_B(arr, nb)                                                      \
  {                                                                        \
    _Pragma("unroll") for (int nn = 0; nn < 2; ++nn)                       \
    _Pragma("unroll") for (int ss = 0; ss < 2; ++ss) {                     \
      int rB = wc * 64 + ((nb) + nn) * 16 + rl;                            \
      arr[nn][ss] = *(const bf16x8*)&Bs[c][(rB << 6) +                     \
                                           (((ss * 4 + q) ^ (rB & 7)) << 3)];\
    }                                                                      \
  }

#define MMQ(mb, arr, nb)                                                   \
  {                                                                        \
    _Pragma("unroll") for (int ss = 0; ss < 2; ++ss)                       \
    _Pragma("unroll") for (int mm = 0; mm < 4; ++mm)                       \
    _Pragma("unroll") for (int nn = 0; nn < 2; ++nn)                       \
      acc[(mb) + mm][(nb) + nn] = __builtin_amdgcn_mfma_f32_16x16x32_bf16( \
          a[mm][ss], arr[nn][ss], acc[(mb) + mm][(nb) + nn], 0, 0, 0);     \
  }

  // prologue: stage K-tile 0 into buf 0
  STAGE(0, 0);
  asm volatile("s_waitcnt vmcnt(0)" ::: "memory");
  __builtin_amdgcn_s_barrier();
  __builtin_amdgcn_sched_barrier(0);

  for (int t = 0; t < 8; ++t) {
    int c = t & 1;
    // phase 1: prefetch next tile (4-phase issue->wait distance) + quadrant
    if (t < 7) STAGE(c ^ 1, (t + 1) * BKT);
    RD_A(0);
    RD_B(bA, 0);
    __builtin_amdgcn_s_setprio(1);
    MMQ(0, bA, 0);
    __builtin_amdgcn_s_setprio(0);
    __builtin_amdgcn_s_barrier();
    // phase 2
    RD_B(bB, 2);
    __builtin_amdgcn_s_setprio(1);
    MMQ(0, bB, 2);
    __builtin_amdgcn_s_setprio(0);
    __builtin_amdgcn_s_barrier();
    // phase 3
    RD_A(4);
    __builtin_amdgcn_s_setprio(1);
    MMQ(4, bB, 2);
    __builtin_amdgcn_s_setprio(0);
    __builtin_amdgcn_s_barrier();
    // phase 4 (no reads; buffer handoff)
    __builtin_amdgcn_s_setprio(1);
    MMQ(4, bA, 0);
    __builtin_amdgcn_s_setprio(0);
    asm volatile("s_waitcnt vmcnt(0)" ::: "memory");
    __builtin_amdgcn_s_barrier();
    __builtin_amdgcn_sched_barrier(0);
  }
#undef STAGE
#undef RD_A
#undef RD_B
#undef MMQ

  // epilogue: +c, tanh, *V, reduce over u (this block's 256-u slice)
  float cu[4], vv[4];
#pragma unroll
  for (int n = 0; n < 4; ++n) {
    int col = u0 + wc * 64 + n * 16 + rl;
    cu[n] = C[(size_t)(b * H_ + h) * U_ + col];
    vv[n] = V[h * U_ + col];
  }
  float part[32];
#pragma unroll
  for (int m = 0; m < 8; ++m)
#pragma unroll
    for (int j = 0; j < 4; ++j) {
      float s = 0.f;
#pragma unroll
      for (int n = 0; n < 4; ++n)
        s += fast_tanh2(acc[m][n][j] + cu[n]) * vv[n];
      part[m * 4 + j] = s;
    }
#pragma unroll
  for (int p = 0; p < 32; ++p) {
    float v = part[p];
    v += __shfl_xor(v, 1, 64);
    v += __shfl_xor(v, 2, 64);
    v += __shfl_xor(v, 4, 64);
    v += __shfl_xor(v, 8, 64);
    part[p] = v;
  }
  if (rl == 0) {
#pragma unroll
    for (int m = 0; m < 8; ++m)
#pragma unroll
      for (int j = 0; j < 4; ++j)
        redsm[wc][wr * 128 + m * 16 + q * 4 + j] = part[m * 4 + j];
  }
  __syncthreads();
  if (tid < 256) {
    float s = redsm[0][tid] + redsm[1][tid] + redsm[2][tid] + redsm[3][tid];
    pscore[((size_t)ut * B_ * H_ + b * H_ + h) * L_ + l0 + tid] = s;
  }
}

// ---------------------------------------------------------------------------
// softmax over L per (b,h): sums the 2 u-slice partial scores (bV omitted --
// it is uniform over L and cancels in softmax), writes attn (aliases pscore
// slice 0 -- safe: row is cached in LDS before any write) + aw_out.
// ---------------------------------------------------------------------------
__global__ __launch_bounds__(256) void softmax_kernel(
    const float* __restrict__ pscore, float* __restrict__ attn,
    float* __restrict__ aw_out) {
  int bh = blockIdx.x;
  int b = bh / H_, h = bh % H_;
  const float* p0 = pscore + (size_t)bh * L_;
  const float* p1 = pscore + ((size_t)B_ * H_ + bh) * L_;
  __shared__ float sv[L_];  // 8 KB
  __shared__ float red[256];

  for (int i = threadIdx.x; i < L_ / 4; i += 256) {
    float4 a = ((const float4*)p0)[i];
    float4 c = ((const float4*)p1)[i];
    a.x += c.x; a.y += c.y; a.z += c.z; a.w += c.w;
    ((float4*)sv)[i] = a;
  }
  __syncthreads();

  float m = -1e30f;
  for (int l = threadIdx.x; l < L_; l += 256) m = fmaxf(m, sv[l]);
  red[threadIdx.x] = m;
  __syncthreads();
  for (int st = 128; st > 0; st >>= 1) {
    if (threadIdx.x < st)
      red[threadIdx.x] = fmaxf(red[threadIdx.x], red[threadIdx.x + st]);
    __syncthreads();
  }
  m = red[0];
  __syncthreads();

  float sum = 0.f;
  for (int l = threadIdx.x; l < L_; l += 256) sum += __expf(sv[l] - m);
  red[threadIdx.x] = sum;
  __syncthreads();
  for (int st = 128; st > 0; st >>= 1) {
    if (threadIdx.x < st) red[threadIdx.x] += red[threadIdx.x + st];
    __syncthreads();
  }
  float inv = 1.f / red[0];

  for (int l = threadIdx.x; l < L_; l += 256) {
    float a = __expf(sv[l] - m) * inv;
    attn[(size_t)bh * L_ + l] = a;
    aw_out[((size_t)b * L_ + l) * H_ + h] = a;
  }
}

// ---------------------------------------------------------------------------
// context split-L: partial[lz][b,h,d] = sum_{l in chunk lz} attn*F
// ---------------------------------------------------------------------------
__global__ __launch_bounds__(256) void context_part_kernel(
    const float* __restrict__ F, const float* __restrict__ attn,
    float* __restrict__ partial) {
  int b = blockIdx.x;
  int d0 = blockIdx.y * 64;
  int lz = blockIdx.z;
  int td = threadIdx.x & 63;
  int tl = threadIdx.x >> 6;  // 0..3

  __shared__ float as[H_][256];  // 8 KB
  for (int idx = threadIdx.x; idx < H_ * 256; idx += 256)
    as[idx >> 8][idx & 255] =
        attn[((size_t)b * H_ + (idx >> 8)) * L_ + lz * 256 + (idx & 255)];
  __syncthreads();

  float acc[H_] = {};
  for (int l = tl; l < 256; l += 4) {
    float f = F[((size_t)b * L_ + lz * 256 + l) * DF + d0 + td];
#pragma unroll
    for (int h = 0; h < H_; h++) acc[h] += as[h][l] * f;
  }

  __shared__ float red[4][H_][64];  // 8 KB
#pragma unroll
  for (int h = 0; h < H_; h++) red[tl][h][td] = acc[h];
  __syncthreads();
  if (tl == 0) {
#pragma unroll
    for (int h = 0; h < H_; h++) {
      float v = red[0][h][td] + red[1][h][td] + red[2][h][td] + red[3][h][td];
      partial[(size_t)lz * B_ * H_ * DF + ((size_t)b * H_ + h) * DF + d0 + td] =
          v;
    }
  }
}

__global__ __launch_bounds__(256) void context_combine_kernel(
    const float* __restrict__ partial, float* __restrict__ ctx_out) {
  int i = blockIdx.x * 256 + threadIdx.x;  // over B*H*DF
  float s = 0.f;
#pragma unroll
  for (int z = 0; z < 8; z++) s += partial[(size_t)z * B_ * H_ * DF + i];
  ctx_out[i] = s;
}

// ---------------------------------------------------------------------------
extern "C" void kernel_launch(void* const* d_in, const int* in_sizes, int n_in,
                              void* d_out, int out_size, void* d_ws,
                              size_t ws_size, hipStream_t stream) {
  const float* features = (const float*)d_in[0];  // [B,L,Df]
  const float* hidden   = (const float*)d_in[1];  // [B,H,Dh]
  const float* W1       = (const float*)d_in[2];  // [H,Df,U]
  const float* b1       = (const float*)d_in[3];  // [H,U]
  const float* W2       = (const float*)d_in[4];  // [H,Dh,U]
  const float* b2       = (const float*)d_in[5];  // [H,U]
  const float* V        = (const float*)d_in[6];  // [H,U]
  // d_in[7] = bV: uniform over L per (b,h) -> cancels in softmax; unused.

  float* out = (float*)d_out;
  float* ctx_out = out;                 // [B,H,Df]
  float* aw_out  = out + B_ * H_ * DF;  // [B,L,H,1]

  // ws layout (floats): c | pscore[2] | cpart, then bf16: Abf | W1T
  //  - hproj partials (8*B*H*U = 524288 f) alias pscore (524288 f): fully
  //    consumed by hproj_combine before score_kernel writes pscore.
  //  - attn aliases pscore slice 0 (softmax caches row in LDS before write).
  float* c_buf  = (float*)d_ws;
  float* pscore = c_buf + (size_t)B_ * H_ * U_;
  float* attn   = pscore;  // alias (see above)
  float* hpart  = pscore;  // alias (see above)
  float* cpart  = pscore + (size_t)2 * B_ * H_ * L_;  // 8*B*H*DF f
  u16* Abf = (u16*)(cpart + (size_t)8 * B_ * H_ * DF);
  u16* W1T = Abf + (size_t)B_ * L_ * DF;

  convert_kernel<<<16384 + 2048, 256, 0, stream>>>(features, Abf, W1, W1T);
  hproj_part_kernel<<<dim3(H_, U_ / 128, 8), 128, 0, stream>>>(hidden, W2,
                                                               hpart);
  hproj_combine_kernel<<<(B_ * H_ * U_) / 256, 256, 0, stream>>>(hpart, b1, b2,
                                                                 c_buf);
  score_kernel<<<dim3(16, B_, H_), 512, 0, stream>>>(Abf, W1T, c_buf, V,
                                                     pscore);
  softmax_kernel<<<B_ * H_, 256, 0, stream>>>(pscore, attn, aw_out);
  context_part_kernel<<<dim3(B_, DF / 64, 8), 256, 0, stream>>>(features, attn,
                                                                cpart);
  context_combine_kernel<<<(B_ * H_ * DF) / 256, 256, 0, stream>>>(cpart,
                                                                   ctx_out);
}

// Round 7
// 267.421 us; speedup vs baseline: 1.0263x; 1.0263x over previous
//
#include <hip/hip_runtime.h>
#include <hip/hip_bf16.h>

// Problem dims
#define B_ 16
#define L_ 2048
#define DF 512
#define H_ 8
#define DH 512
#define U_ 512

typedef unsigned short u16;
typedef __attribute__((ext_vector_type(8))) short bf16x8;
typedef __attribute__((ext_vector_type(4))) float f32x4;

__device__ __forceinline__ u16 f2bf(float x) {
  __hip_bfloat16 h = __float2bfloat16(x);
  u16 u;
  __builtin_memcpy(&u, &h, 2);
  return u;
}

__device__ __forceinline__ void load_lds16(const void* g, void* l) {
  __builtin_amdgcn_global_load_lds(
      (const __attribute__((address_space(1))) void*)g,
      (__attribute__((address_space(3))) void*)l, 16, 0, 0);
}

// tanh(x) = 1 - 2/(1+e^{2x}); exact at +-inf, ~1e-6 abs err.
__device__ __forceinline__ float fast_tanh2(float x) {
  float e = __expf(2.f * x);
  return 1.f - __fdividef(2.f, e + 1.f);
}

// ---------------------------------------------------------------------------
// Merged conversion kernel:
//  blocks [0, 16384): features fp32 -> bf16 [B,L,DF], 4 elems/thread
//  blocks [16384, 18432): W1 [H,DF,U] -> W1T [H,U,DF] bf16 (32x32 transpose)
// ---------------------------------------------------------------------------
__global__ __launch_bounds__(256) void convert_kernel(
    const float* __restrict__ F, u16* __restrict__ Abf,
    const float* __restrict__ W1, u16* __restrict__ W1T) {
  __shared__ float t[32][33];
  if (blockIdx.x < 16384) {
    size_t i = ((size_t)blockIdx.x * 256 + threadIdx.x) * 4;
    float4 v = *(const float4*)(F + i);
    ushort4 o;
    o.x = f2bf(v.x); o.y = f2bf(v.y); o.z = f2bf(v.z); o.w = f2bf(v.w);
    *(ushort4*)(Abf + i) = o;
  } else {
    int bid = blockIdx.x - 16384;
    int d0 = (bid & 15) * 32, u0 = ((bid >> 4) & 15) * 32, h = bid >> 8;
    const float* src = W1 + (size_t)h * DF * U_;
    u16* dst = W1T + (size_t)h * U_ * DF;
#pragma unroll
    for (int i = 0; i < 4; ++i) {
      int idx = threadIdx.x + i * 256;
      int r = idx >> 5, c = idx & 31;
      t[r][c] = src[(size_t)(d0 + r) * U_ + u0 + c];
    }
    __syncthreads();
#pragma unroll
    for (int i = 0; i < 4; ++i) {
      int idx = threadIdx.x + i * 256;
      int r = idx >> 5, c = idx & 31;  // r: u index, c: d index
      dst[(size_t)(u0 + r) * DF + d0 + c] = f2bf(t[c][r]);
    }
  }
}

// ---------------------------------------------------------------------------
// hproj split-d: partial[z,b,h,u] = sum_{d in chunk z} hidden*W2
// ---------------------------------------------------------------------------
__global__ __launch_bounds__(128) void hproj_part_kernel(
    const float* __restrict__ hidden, const float* __restrict__ W2,
    float* __restrict__ partial) {
  int h = blockIdx.x;
  int u = blockIdx.y * 128 + threadIdx.x;
  int d0 = blockIdx.z * 64;
  __shared__ float hs[B_][64];
  for (int idx = threadIdx.x; idx < B_ * 64; idx += 128) {
    int b = idx >> 6, d = idx & 63;
    hs[b][d] = hidden[(size_t)(b * H_ + h) * DH + d0 + d];
  }
  __syncthreads();
  float acc[B_];
#pragma unroll
  for (int b = 0; b < B_; b++) acc[b] = 0.f;
  const float* w2p = W2 + ((size_t)h * DH + d0) * U_ + u;
  for (int d = 0; d < 64; d++) {
    float w = w2p[(size_t)d * U_];
#pragma unroll
    for (int b = 0; b < B_; b++) acc[b] += hs[b][d] * w;
  }
#pragma unroll
  for (int b = 0; b < B_; b++)
    partial[(((size_t)blockIdx.z * B_ + b) * H_ + h) * U_ + u] = acc[b];
}

__global__ __launch_bounds__(256) void hproj_combine_kernel(
    const float* __restrict__ partial, const float* __restrict__ b1,
    const float* __restrict__ b2, float* __restrict__ c) {
  int i = blockIdx.x * 256 + threadIdx.x;  // over B*H*U
  int hu = i & (H_ * U_ - 1);
  float s = b1[hu] + b2[hu];
#pragma unroll
  for (int z = 0; z < 8; z++) s += partial[(size_t)z * B_ * H_ * U_ + i];
  c[i] = s;
}

// ---------------------------------------------------------------------------
// score kernel, faithful 8-phase 256x256 (T2+T3+T4+T5, derived waits):
//  - interleaved wave rows: rA = m*32+wr*16+rl, rB = n*64+wc*16+rl so each
//    quadrant-phase touches exactly one A-half / one B-half of the K-tile
//  - per phase: {ds_read subtile | stage 1 half-tile} ; barrier ; lgkmcnt(0);
//    sched_barrier ; setprio(1) ; 16 MFMA ; setprio(0) ; [vmcnt(4)] ; barrier
//  - staging of tile t+1 spread SA0,SB0,SB1,SA1 over tile t's 4 phases;
//    vmcnt(4) at phase closes 1,2,4 (derived: each half lands >=3 phases
//    after issue); vmcnt(2)/(0) only in the tail tile.
// grid (16 = 8 mt x 2 ut, B, H), block 512 (8 waves, 2M x 4N).
// ---------------------------------------------------------------------------
#define BKT 64

__global__ __launch_bounds__(512, 2) void score_kernel(
    const u16* __restrict__ Abf, const u16* __restrict__ W1T,
    const float* __restrict__ C, const float* __restrict__ V,
    float* __restrict__ pscore) {
  int gx = blockIdx.x;
  int mt = gx >> 1, ut = gx & 1;
  int l0 = mt * 256, u0 = ut * 256;
  int b = blockIdx.y, h = blockIdx.z;
  int tid = threadIdx.x;
  int lane = tid & 63, wid = tid >> 6;
  int wr = wid >> 2, wc = wid & 3;  // 2 x 4 waves
  int rl = lane & 15, q = lane >> 4;

  __shared__ u16 As[2][256 * BKT];  // 32 KB each
  __shared__ u16 Bs[2][256 * BKT];
  __shared__ float redsm[4][256];   // 4 KB

  const u16* Fb = Abf + ((size_t)b * L_ + l0) * DF;
  const u16* Wh = W1T + ((size_t)h * U_ + u0) * DF;

  f32x4 acc[8][4];
#pragma unroll
  for (int m = 0; m < 8; ++m)
#pragma unroll
    for (int n = 0; n < 4; ++n)
#pragma unroll
      for (int j = 0; j < 4; ++j) acc[m][n][j] = 0.f;

  // Half-tile staging (128 rows x 64 k = 16 KB = 2 loads/thread). Physical
  // 16B chunk (row, ch) holds logical chunk ch ^ (row&7); same XOR on read.
#define STAGE_A(bufi, half, kb)                                            \
  {                                                                        \
    _Pragma("unroll") for (int i_ = 0; i_ < 2; ++i_) {                     \
      int idx_ = i_ * 512 + tid;                                           \
      int row_ = idx_ >> 3;                                                \
      int ke_ = ((idx_ & 7) ^ (row_ & 7)) << 3;                            \
      load_lds16(Fb + (((size_t)((half)*128 + row_)) << 9) + (kb) + ke_,   \
                 &As[bufi][(half)*8192 + idx_ * 8]);                       \
    }                                                                      \
  }
#define STAGE_B(bufi, half, kb)                                            \
  {                                                                        \
    _Pragma("unroll") for (int i_ = 0; i_ < 2; ++i_) {                     \
      int idx_ = i_ * 512 + tid;                                           \
      int row_ = idx_ >> 3;                                                \
      int ke_ = ((idx_ & 7) ^ (row_ & 7)) << 3;                            \
      load_lds16(Wh + (((size_t)((half)*128 + row_)) << 9) + (kb) + ke_,   \
                 &Bs[bufi][(half)*8192 + idx_ * 8]);                       \
    }                                                                      \
  }

  bf16x8 aX[4][2], bA[2][2], bB[2][2];

#define RD_A(mb, bufi)                                                     \
  {                                                                        \
    _Pragma("unroll") for (int mm = 0; mm < 4; ++mm)                       \
    _Pragma("unroll") for (int ss = 0; ss < 2; ++ss) {                     \
      int rA = ((mb) + mm) * 32 + wr * 16 + rl;                            \
      aX[mm][ss] = *(const bf16x8*)&As[bufi][(rA << 6) +                   \
                                    (((ss * 4 + q) ^ (rA & 7)) << 3)];     \
    }                                                                      \
  }
#define RD_B(arr, nb, bufi)                                                \
  {                                                                        \
    _Pragma("unroll") for (int nn = 0; nn < 2; ++nn)                       \
    _Pragma("unroll") for (int ss = 0; ss < 2; ++ss) {                     \
      int rB = ((nb) + nn) * 64 + wc * 16 + rl;                            \
      arr[nn][ss] = *(const bf16x8*)&Bs[bufi][(rB << 6) +                  \
                                     (((ss * 4 + q) ^ (rB & 7)) << 3)];    \
    }                                                                      \
  }
#define MMQ(mb, arr, nb)                                                   \
  {                                                                        \
    _Pragma("unroll") for (int ss = 0; ss < 2; ++ss)                       \
    _Pragma("unroll") for (int mm = 0; mm < 4; ++mm)                       \
    _Pragma("unroll") for (int nn = 0; nn < 2; ++nn)                       \
      acc[(mb) + mm][(nb) + nn] = __builtin_amdgcn_mfma_f32_16x16x32_bf16( \
          aX[mm][ss], arr[nn][ss], acc[(mb) + mm][(nb) + nn], 0, 0, 0);    \
  }

#define LGKM0_SCHED                                                        \
  asm volatile("s_waitcnt lgkmcnt(0)" ::: "memory");                       \
  __builtin_amdgcn_sched_barrier(0)

  // prologue: tile 0 (buf 0), all 4 half-tiles; wait first two landed
  STAGE_A(0, 0, 0);
  STAGE_B(0, 0, 0);
  STAGE_B(0, 1, 0);
  STAGE_A(0, 1, 0);
  asm volatile("s_waitcnt vmcnt(4)" ::: "memory");
  __builtin_amdgcn_s_barrier();

#pragma unroll 1
  for (int t = 0; t < 7; ++t) {
    int cc = t & 1;
    int kb = (t + 1) * BKT;
    // phase 1: Q1 (m0-3 x n0-1) -- reads A-half0, B-half0
    RD_A(0, cc);
    RD_B(bA, 0, cc);
    STAGE_A(cc ^ 1, 0, kb);  // SA0(t+1)
    __builtin_amdgcn_s_barrier();
    LGKM0_SCHED;
    __builtin_amdgcn_s_setprio(1);
    MMQ(0, bA, 0);
    __builtin_amdgcn_s_setprio(0);
    asm volatile("s_waitcnt vmcnt(4)" ::: "memory");
    __builtin_amdgcn_s_barrier();
    // phase 2: Q2 (m0-3 x n2-3) -- reads B-half1
    RD_B(bB, 2, cc);
    STAGE_B(cc ^ 1, 0, kb);  // SB0(t+1)
    __builtin_amdgcn_s_barrier();
    LGKM0_SCHED;
    __builtin_amdgcn_s_setprio(1);
    MMQ(0, bB, 2);
    __builtin_amdgcn_s_setprio(0);
    asm volatile("s_waitcnt vmcnt(4)" ::: "memory");
    __builtin_amdgcn_s_barrier();
    // phase 3: Q3 (m4-7 x n2-3) -- reads A-half1
    RD_A(4, cc);
    STAGE_B(cc ^ 1, 1, kb);  // SB1(t+1)
    __builtin_amdgcn_s_barrier();
    LGKM0_SCHED;
    __builtin_amdgcn_s_setprio(1);
    MMQ(4, bB, 2);
    __builtin_amdgcn_s_setprio(0);
    __builtin_amdgcn_s_barrier();
    // phase 4: Q4 (m4-7 x n0-1) -- no new reads
    STAGE_A(cc ^ 1, 1, kb);  // SA1(t+1)
    __builtin_amdgcn_s_barrier();
    __builtin_amdgcn_s_setprio(1);
    MMQ(4, bA, 0);
    __builtin_amdgcn_s_setprio(0);
    asm volatile("s_waitcnt vmcnt(4)" ::: "memory");
    __builtin_amdgcn_s_barrier();
  }
  // tail tile 7 (buf 1), no staging; drain waits
  RD_A(0, 1);
  RD_B(bA, 0, 1);
  __builtin_amdgcn_s_barrier();
  LGKM0_SCHED;
  __builtin_amdgcn_s_setprio(1);
  MMQ(0, bA, 0);
  __builtin_amdgcn_s_setprio(0);
  asm volatile("s_waitcnt vmcnt(2)" ::: "memory");
  __builtin_amdgcn_s_barrier();
  RD_B(bB, 2, 1);
  __builtin_amdgcn_s_barrier();
  LGKM0_SCHED;
  __builtin_amdgcn_s_setprio(1);
  MMQ(0, bB, 2);
  __builtin_amdgcn_s_setprio(0);
  asm volatile("s_waitcnt vmcnt(0)" ::: "memory");
  __builtin_amdgcn_s_barrier();
  RD_A(4, 1);
  LGKM0_SCHED;
  __builtin_amdgcn_s_setprio(1);
  MMQ(4, bB, 2);
  MMQ(4, bA, 0);
  __builtin_amdgcn_s_setprio(0);
#undef STAGE_A
#undef STAGE_B
#undef RD_A
#undef RD_B
#undef MMQ
#undef LGKM0_SCHED

  // epilogue: +c, tanh, *V, reduce over u (this block's 256-u slice)
  float cu[4], vv[4];
#pragma unroll
  for (int n = 0; n < 4; ++n) {
    int col = u0 + n * 64 + wc * 16 + rl;
    cu[n] = C[(size_t)(b * H_ + h) * U_ + col];
    vv[n] = V[h * U_ + col];
  }
  float part[32];
#pragma unroll
  for (int m = 0; m < 8; ++m)
#pragma unroll
    for (int j = 0; j < 4; ++j) {
      float s = 0.f;
#pragma unroll
      for (int n = 0; n < 4; ++n)
        s += fast_tanh2(acc[m][n][j] + cu[n]) * vv[n];
      part[m * 4 + j] = s;
    }
#pragma unroll
  for (int p = 0; p < 32; ++p) {
    float v = part[p];
    v += __shfl_xor(v, 1, 64);
    v += __shfl_xor(v, 2, 64);
    v += __shfl_xor(v, 4, 64);
    v += __shfl_xor(v, 8, 64);
    part[p] = v;
  }
  __syncthreads();  // all LDS reads of As/Bs done before redsm reuse window
  if (rl == 0) {
#pragma unroll
    for (int m = 0; m < 8; ++m)
#pragma unroll
      for (int j = 0; j < 4; ++j)
        redsm[wc][m * 32 + wr * 16 + q * 4 + j] = part[m * 4 + j];
  }
  __syncthreads();
  if (tid < 256) {
    float s = redsm[0][tid] + redsm[1][tid] + redsm[2][tid] + redsm[3][tid];
    pscore[((size_t)ut * B_ * H_ + b * H_ + h) * L_ + l0 + tid] = s;
  }
}

// ---------------------------------------------------------------------------
// softmax over L per (b,h): sums the 2 u-slice partial scores (bV omitted --
// uniform over L, cancels in softmax), writes attn + aw_out [B,L,H,1].
// ---------------------------------------------------------------------------
__global__ __launch_bounds__(256) void softmax_kernel(
    const float* __restrict__ pscore, float* __restrict__ attn,
    float* __restrict__ aw_out) {
  int bh = blockIdx.x;
  int b = bh / H_, h = bh % H_;
  const float* p0 = pscore + (size_t)bh * L_;
  const float* p1 = pscore + ((size_t)B_ * H_ + bh) * L_;
  __shared__ float sv[L_];  // 8 KB
  __shared__ float red[256];

  for (int i = threadIdx.x; i < L_ / 4; i += 256) {
    float4 a = ((const float4*)p0)[i];
    float4 c = ((const float4*)p1)[i];
    a.x += c.x; a.y += c.y; a.z += c.z; a.w += c.w;
    ((float4*)sv)[i] = a;
  }
  __syncthreads();

  float m = -1e30f;
  for (int l = threadIdx.x; l < L_; l += 256) m = fmaxf(m, sv[l]);
  red[threadIdx.x] = m;
  __syncthreads();
  for (int st = 128; st > 0; st >>= 1) {
    if (threadIdx.x < st)
      red[threadIdx.x] = fmaxf(red[threadIdx.x], red[threadIdx.x + st]);
    __syncthreads();
  }
  m = red[0];
  __syncthreads();

  float sum = 0.f;
  for (int l = threadIdx.x; l < L_; l += 256) sum += __expf(sv[l] - m);
  red[threadIdx.x] = sum;
  __syncthreads();
  for (int st = 128; st > 0; st >>= 1) {
    if (threadIdx.x < st) red[threadIdx.x] += red[threadIdx.x + st];
    __syncthreads();
  }
  float inv = 1.f / red[0];

  for (int l = threadIdx.x; l < L_; l += 256) {
    float a = __expf(sv[l] - m) * inv;
    attn[(size_t)bh * L_ + l] = a;
    aw_out[((size_t)b * L_ + l) * H_ + h] = a;
  }
}

// ---------------------------------------------------------------------------
// context split-L: partial[lz][b,h,d] = sum_{l in chunk lz} attn*F
// ---------------------------------------------------------------------------
__global__ __launch_bounds__(256) void context_part_kernel(
    const float* __restrict__ F, const float* __restrict__ attn,
    float* __restrict__ partial) {
  int b = blockIdx.x;
  int d0 = blockIdx.y * 64;
  int lz = blockIdx.z;
  int td = threadIdx.x & 63;
  int tl = threadIdx.x >> 6;  // 0..3

  __shared__ float as[H_][256];  // 8 KB
  for (int idx = threadIdx.x; idx < H_ * 256; idx += 256)
    as[idx >> 8][idx & 255] =
        attn[((size_t)b * H_ + (idx >> 8)) * L_ + lz * 256 + (idx & 255)];
  __syncthreads();

  float acc[H_] = {};
  for (int l = tl; l < 256; l += 4) {
    float f = F[((size_t)b * L_ + lz * 256 + l) * DF + d0 + td];
#pragma unroll
    for (int h = 0; h < H_; h++) acc[h] += as[h][l] * f;
  }

  __shared__ float red[4][H_][64];  // 8 KB
#pragma unroll
  for (int h = 0; h < H_; h++) red[tl][h][td] = acc[h];
  __syncthreads();
  if (tl == 0) {
#pragma unroll
    for (int h = 0; h < H_; h++) {
      float v = red[0][h][td] + red[1][h][td] + red[2][h][td] + red[3][h][td];
      partial[(size_t)lz * B_ * H_ * DF + ((size_t)b * H_ + h) * DF + d0 + td] =
          v;
    }
  }
}

__global__ __launch_bounds__(256) void context_combine_kernel(
    const float* __restrict__ partial, float* __restrict__ ctx_out) {
  int i = blockIdx.x * 256 + threadIdx.x;  // over B*H*DF
  float s = 0.f;
#pragma unroll
  for (int z = 0; z < 8; z++) s += partial[(size_t)z * B_ * H_ * DF + i];
  ctx_out[i] = s;
}

// ---------------------------------------------------------------------------
extern "C" void kernel_launch(void* const* d_in, const int* in_sizes, int n_in,
                              void* d_out, int out_size, void* d_ws,
                              size_t ws_size, hipStream_t stream) {
  const float* features = (const float*)d_in[0];  // [B,L,Df]
  const float* hidden   = (const float*)d_in[1];  // [B,H,Dh]
  const float* W1       = (const float*)d_in[2];  // [H,Df,U]
  const float* b1       = (const float*)d_in[3];  // [H,U]
  const float* W2       = (const float*)d_in[4];  // [H,Dh,U]
  const float* b2       = (const float*)d_in[5];  // [H,U]
  const float* V        = (const float*)d_in[6];  // [H,U]
  // d_in[7] = bV: uniform over L per (b,h) -> cancels in softmax; unused.

  float* out = (float*)d_out;
  float* ctx_out = out;                 // [B,H,Df]
  float* aw_out  = out + B_ * H_ * DF;  // [B,L,H,1]

  // ws layout (floats): c | pscore[2] | cpart, then bf16: Abf | W1T
  //  - hproj partials alias pscore: fully consumed by hproj_combine before
  //    score_kernel writes pscore.
  //  - attn aliases pscore slice 0 (softmax caches row in LDS before write).
  float* c_buf  = (float*)d_ws;
  float* pscore = c_buf + (size_t)B_ * H_ * U_;
  float* attn   = pscore;  // alias (see above)
  float* hpart  = pscore;  // alias (see above)
  float* cpart  = pscore + (size_t)2 * B_ * H_ * L_;  // 8*B*H*DF f
  u16* Abf = (u16*)(cpart + (size_t)8 * B_ * H_ * DF);
  u16* W1T = Abf + (size_t)B_ * L_ * DF;

  convert_kernel<<<16384 + 2048, 256, 0, stream>>>(features, Abf, W1, W1T);
  hproj_part_kernel<<<dim3(H_, U_ / 128, 8), 128, 0, stream>>>(hidden, W2,
                                                               hpart);
  hproj_combine_kernel<<<(B_ * H_ * U_) / 256, 256, 0, stream>>>(hpart, b1, b2,
                                                                 c_buf);
  score_kernel<<<dim3(16, B_, H_), 512, 0, stream>>>(Abf, W1T, c_buf, V,
                                                     pscore);
  softmax_kernel<<<B_ * H_, 256, 0, stream>>>(pscore, attn, aw_out);
  context_part_kernel<<<dim3(B_, DF / 64, 8), 256, 0, stream>>>(features, attn,
                                                                cpart);
  context_combine_kernel<<<(B_ * H_ * DF) / 256, 256, 0, stream>>>(cpart,
                                                                   ctx_out);
}